// Round 7
// baseline (36.629 us; speedup 1.0000x reference)
//
#include <hip/hip_runtime.h>
#include <hip/hip_bf16.h>
#include <math.h>

// Problem constants: N=32768 points, D=16, F=4096 features, M=16
#define NPTS  32768
#define DIMD  16
#define NFEAT 4096
#define MDIM  16

typedef short bf16x8 __attribute__((ext_vector_type(8)));
typedef float f32x16 __attribute__((ext_vector_type(16)));
typedef float f32x4v __attribute__((ext_vector_type(4)));
typedef float f32x2  __attribute__((ext_vector_type(2)));

constexpr float SCALE  = 0.02209708691207961f;   // sqrt(2/4096), folded into W at prep
constexpr float INV2PI = 0.15915494309189535f;   // folded into a,b at prep (cos in revs)

// ---- d_ws scratch layout ----
// A1 (a*INV2PI bf16 A-frags): [128 steps][64 lanes][8 bf16]    @ 0       (128 KiB)
// A2 (W*SCALE bf16 A-frags):  [128 steps][2 tiles][64][8 bf16] @ 128 KiB (256 KiB)
// BS (b*INV2PI fp32):         [4096]                           @ 384 KiB ( 16 KiB)
#define WS_A1_OFF 0
#define WS_A2_OFF 131072
#define WS_BS_OFF 393216
#define WS_NEEDED 409600

__device__ __forceinline__ unsigned short f2bf(float x) {  // RNE f32->bf16
    unsigned int u = __float_as_uint(x);
    u += 0x7fff + ((u >> 16) & 1);
    return (unsigned short)(u >> 16);
}
__device__ __forceinline__ unsigned int cvtpk(float lo, float hi) {
    unsigned int r;
    asm("v_cvt_pk_bf16_f32 %0, %1, %2" : "=v"(r) : "v"(lo), "v"(hi));
    return r;
}
// a' = [a_lo | b_lo], b' = [a_hi | b_hi]  (lane halves)
__device__ __forceinline__ void swap32(unsigned int& a, unsigned int& b) {
    asm("v_permlane32_swap_b32 %0, %1" : "+v"(a), "+v"(b));
}

// cos(2*pi*t) for a pair of values on the VALU (packed v_pk_* math), freeing
// the trans pipe. r = t - rint(t) in [-0.5,0.5]; degree-6 Taylor in z = r^2.
// Max abs err 1.0e-4 (at r=+-0.5); verified P(0)=1, P(0.0625)=0, P(0.25)=-0.9999.
__device__ __forceinline__ f32x2 cos2pi_pair(float t0, float t1) {
    f32x2 r;
    r[0] = t0 - __builtin_rintf(t0);
    r[1] = t1 - __builtin_rintf(t1);
    f32x2 z = r * r;
    f32x2 p = z * 7.903537f   - 26.426257f;
    p = p * z + 60.244641f;
    p = p * z - 85.456817f;
    p = p * z + 64.939394f;
    p = p * z - 19.7392088f;
    p = p * z + 1.0f;
    return p;
}

// Wave-parallel prep: block=256 (4 waves), one step per block; wave roles:
// w0 -> A1 frags, w1 -> A2 q=0, w2 -> A2 q=1 (zero-padded m>=16), w3 -> bias.
// MFMA 32x32x16 A-layout: lane l holds row (l&31), k = (l>>5)*8 + j.
__global__ __launch_bounds__(256) void km_prep(
    const float* __restrict__ a, const float* __restrict__ b, const float* __restrict__ W,
    unsigned short* __restrict__ ws_a1, unsigned short* __restrict__ ws_a2,
    float* __restrict__ ws_bs)
{
    const int s  = blockIdx.x;    // K-step 0..127 (32 features each)
    const int wv = threadIdx.x >> 6;
    const int l  = threadIdx.x & 63;
    const int h  = l >> 5;
    const int nl = l & 31;

    if (wv == 0) {        // A1: rows = features 32s+(l&31), k = dims 8h..8h+7, *1/2pi
        const int f = 32 * s + nl;
        const float* ap = a + f * DIMD + 8 * h;
        union { unsigned short u[8]; bf16x8 v; } cv;
        #pragma unroll
        for (int j = 0; j < 8; ++j) cv.u[j] = f2bf(ap[j] * INV2PI);
        *reinterpret_cast<bf16x8*>(ws_a1 + ((size_t)s * 64 + l) * 8) = cv.v;
    } else if (wv <= 2) { // A2 q=wv-1: rows = m (pad m>=16 with 0), k = features
        const int q = wv - 1;
        union { unsigned short u[8]; bf16x8 v; } cv;
        #pragma unroll
        for (int j = 0; j < 8; ++j) {
            float v = 0.f;
            if (nl < MDIM) {
                const int f = 32 * s + 16 * q + 8 * h + j;
                v = W[(size_t)f * MDIM + nl] * SCALE;
            }
            cv.u[j] = f2bf(v);
        }
        *reinterpret_cast<bf16x8*>(ws_a2 + (((size_t)s * 2 + q) * 64 + l) * 8) = cv.v;
    } else {
        if (l < 32) ws_bs[32 * s + l] = b[32 * s + l] * INV2PI;
    }
}

// Hybrid pack: dw0/2/4/6 pairs computed by VALU polynomial (packed fp32),
// dw1/3/5/7 pairs by the trans-pipe v_cos — both pipes run concurrently.
// Positional mapping dw_i = [phi(S[2i]) | phi(S[2i+1])] identical to the
// verified rounds-2-4 pack; only the cos implementation per slot differs.
#define KM_PACK(S, P0, P1)                                                            \
    {                                                                                 \
        float tc0 = __builtin_amdgcn_cosf(S[ 2]);                                     \
        float tc1 = __builtin_amdgcn_cosf(S[ 3]);                                     \
        float tc2 = __builtin_amdgcn_cosf(S[ 6]);                                     \
        float tc3 = __builtin_amdgcn_cosf(S[ 7]);                                     \
        float tc4 = __builtin_amdgcn_cosf(S[10]);                                     \
        float tc5 = __builtin_amdgcn_cosf(S[11]);                                     \
        float tc6 = __builtin_amdgcn_cosf(S[14]);                                     \
        float tc7 = __builtin_amdgcn_cosf(S[15]);                                     \
        f32x2 q0 = cos2pi_pair(S[ 0], S[ 1]);                                         \
        f32x2 q2 = cos2pi_pair(S[ 4], S[ 5]);                                         \
        f32x2 q4 = cos2pi_pair(S[ 8], S[ 9]);                                         \
        f32x2 q6 = cos2pi_pair(S[12], S[13]);                                         \
        unsigned int dw0 = cvtpk(q0[0], q0[1]);                                       \
        unsigned int dw1 = cvtpk(tc0, tc1);                                           \
        unsigned int dw2 = cvtpk(q2[0], q2[1]);                                       \
        unsigned int dw3 = cvtpk(tc2, tc3);                                           \
        unsigned int dw4 = cvtpk(q4[0], q4[1]);                                       \
        unsigned int dw5 = cvtpk(tc4, tc5);                                           \
        unsigned int dw6 = cvtpk(q6[0], q6[1]);                                       \
        unsigned int dw7 = cvtpk(tc6, tc7);                                           \
        swap32(dw0, dw2); swap32(dw1, dw3);                                           \
        swap32(dw4, dw6); swap32(dw5, dw7);                                           \
        union { unsigned int u[4]; bf16x8 v; } q0_, q1_;                              \
        q0_.u[0] = dw0; q0_.u[1] = dw1; q0_.u[2] = dw2; q0_.u[3] = dw3;               \
        q1_.u[0] = dw4; q1_.u[1] = dw5; q1_.u[2] = dw6; q1_.u[3] = dw7;               \
        P0 = q0_.v; P1 = q1_.v;                                                       \
    }

// Main: 512 blocks x 512 thr, T=2 n-tiles (round-3 structure, known-good),
// with the hybrid pack. Bias C built once per step, shared by both tiles.
__global__ __launch_bounds__(512, 4) void km_mfma(
    const float* __restrict__ x,
    const unsigned short* __restrict__ ws_a1, const unsigned short* __restrict__ ws_a2,
    const float* __restrict__ ws_bs, float* __restrict__ out)
{
    const int tid = threadIdx.x;
    const int l   = tid & 63;
    const int w   = tid >> 6;          // wave = feature chunk 0..7
    const int h   = l >> 5;
    const int nl  = l & 31;
    const int rowbase = blockIdx.x * 64;

    // GEMM1 B-frags: x^T[16d x 32n] per tile; lane: col n, k = d = 8h+j.
    bf16x8 xf0, xf1;
    {
        union { unsigned short u[8]; bf16x8 v; } c0, c1;
        const float* xp0 = x + (size_t)(rowbase +  0 + nl) * DIMD + 8 * h;
        const float* xp1 = x + (size_t)(rowbase + 32 + nl) * DIMD + 8 * h;
        #pragma unroll
        for (int j = 0; j < 8; ++j) { c0.u[j] = f2bf(xp0[j]); c1.u[j] = f2bf(xp1[j]); }
        xf0 = c0.v; xf1 = c1.v;
    }

    f32x16 acc0, acc1;
    #pragma unroll
    for (int i = 0; i < 16; ++i) { acc0[i] = 0.f; acc1[i] = 0.f; }

    const bool valid = (nl < MDIM);

    #pragma unroll 2
    for (int s = 0; s < 16; ++s) {
        const int sg = w * 16 + s;
        const int F0 = 32 * sg;

        bf16x8 a1 = *reinterpret_cast<const bf16x8*>(ws_a1 + ((size_t)sg * 64 + l) * 8);
        bf16x8 a2t0 = {}, a2t1 = {};
        if (valid) {
            a2t0 = *reinterpret_cast<const bf16x8*>(ws_a2 + (((size_t)sg * 2 + 0) * 64 + l) * 8);
            a2t1 = *reinterpret_cast<const bf16x8*>(ws_a2 + (((size_t)sg * 2 + 1) * 64 + l) * 8);
        }
        // bias C-in built once per step, shared by both tiles:
        // c[r] = bs[F0 + (r&3) + 8*(r>>2) + 4h], prescaled by 1/2pi
        f32x16 c;
        #pragma unroll
        for (int g = 0; g < 4; ++g) {
            f32x4v bb = *reinterpret_cast<const f32x4v*>(ws_bs + F0 + 8 * g + 4 * h);
            c[4*g] = bb[0]; c[4*g+1] = bb[1]; c[4*g+2] = bb[2]; c[4*g+3] = bb[3];
        }

        // ---- tile 0 ----
        {
            f32x16 S = __builtin_amdgcn_mfma_f32_32x32x16_bf16(a1, xf0, c, 0, 0, 0);
            bf16x8 p0, p1;
            KM_PACK(S, p0, p1)
            acc0 = __builtin_amdgcn_mfma_f32_32x32x16_bf16(a2t0, p0, acc0, 0, 0, 0);
            acc0 = __builtin_amdgcn_mfma_f32_32x32x16_bf16(a2t1, p1, acc0, 0, 0, 0);
        }
        // ---- tile 1 ----
        {
            f32x16 S = __builtin_amdgcn_mfma_f32_32x32x16_bf16(a1, xf1, c, 0, 0, 0);
            bf16x8 p0, p1;
            KM_PACK(S, p0, p1)
            acc1 = __builtin_amdgcn_mfma_f32_32x32x16_bf16(a2t0, p0, acc1, 0, 0, 0);
            acc1 = __builtin_amdgcn_mfma_f32_32x32x16_bf16(a2t1, p1, acc1, 0, 0, 0);
        }
    }

    // Cross-wave reduce. acc regs 0..7 hold m=(r&3)+8*(r>>2)+4h for col n=nl
    // (regs 8-15 are the zero m>=16 pad).
    __shared__ float red[2][8][64][8];   // 32 KiB
    #pragma unroll
    for (int r = 0; r < 8; ++r) { red[0][w][l][r] = acc0[r]; red[1][w][l][r] = acc1[r]; }
    __syncthreads();

    const int n_l = tid >> 4;
    const int m   = tid & 15;
    const int li  = n_l + 32 * ((m >> 2) & 1);
    const int r   = (m & 3) + 4 * (m >> 3);
    float s0 = 0.f, s1 = 0.f;
    #pragma unroll
    for (int ww = 0; ww < 8; ++ww) { s0 += red[0][ww][li][r]; s1 += red[1][ww][li][r]; }
    out[(size_t)(rowbase +  0 + n_l) * MDIM + m] = s0;
    out[(size_t)(rowbase + 32 + n_l) * MDIM + m] = s1;
}

// ---------------- fallback (round-1 kernel, known-correct) ----------------
constexpr int FB_WAVES = 8, FB_BLOCK = 512, FB_ROWS = 64, FB_FPW = NFEAT / FB_WAVES;
__global__ __launch_bounds__(FB_BLOCK) void km_fused(
    const float* __restrict__ x, const float* __restrict__ a,
    const float* __restrict__ b, const float* __restrict__ W,
    float* __restrict__ out)
{
    const int lane = threadIdx.x & 63, wave = threadIdx.x >> 6;
    const int row  = blockIdx.x * FB_ROWS + lane;
    float xr[DIMD];
    const float4* xp = reinterpret_cast<const float4*>(x + (size_t)row * DIMD);
    #pragma unroll
    for (int i = 0; i < 4; ++i) {
        float4 v = xp[i];
        xr[4*i] = v.x; xr[4*i+1] = v.y; xr[4*i+2] = v.z; xr[4*i+3] = v.w;
    }
    float acc[MDIM];
    #pragma unroll
    for (int m = 0; m < MDIM; ++m) acc[m] = 0.f;
    const int fbase = __builtin_amdgcn_readfirstlane(wave * FB_FPW);
    const float* ab = a + (size_t)fbase * DIMD;
    const float* wb = W + (size_t)fbase * MDIM;
    const float* bb = b + fbase;
    #pragma unroll 2
    for (int fi = 0; fi < FB_FPW; ++fi) {
        const float* ar = ab + fi * DIMD;
        const float* wr = wb + fi * MDIM;
        float d0 = 0.f, d1 = 0.f, d2 = 0.f, d3 = 0.f;
        #pragma unroll
        for (int d = 0; d < 4; ++d) {
            d0 = fmaf(xr[d], ar[d], d0);       d1 = fmaf(xr[4+d], ar[4+d], d1);
            d2 = fmaf(xr[8+d], ar[8+d], d2);   d3 = fmaf(xr[12+d], ar[12+d], d3);
        }
        float t = ((d0 + d1) + (d2 + d3)) + bb[fi];
        float cc = __builtin_amdgcn_cosf(t * INV2PI);
        #pragma unroll
        for (int m = 0; m < MDIM; ++m) acc[m] = fmaf(cc, wr[m], acc[m]);
    }
    __shared__ float red[FB_WAVES][FB_ROWS][MDIM];
    #pragma unroll
    for (int m = 0; m < MDIM; m += 4)
        *reinterpret_cast<float4*>(&red[wave][lane][m]) =
            make_float4(acc[m], acc[m+1], acc[m+2], acc[m+3]);
    __syncthreads();
    for (int o = threadIdx.x; o < FB_ROWS * MDIM; o += FB_BLOCK) {
        const int rr = o >> 4, m = o & 15;
        float s = 0.f;
        #pragma unroll
        for (int ww = 0; ww < FB_WAVES; ++ww) s += red[ww][rr][m];
        out[((size_t)blockIdx.x * FB_ROWS + rr) * MDIM + m] = s * SCALE;
    }
}

extern "C" void kernel_launch(void* const* d_in, const int* in_sizes, int n_in,
                              void* d_out, int out_size, void* d_ws, size_t ws_size,
                              hipStream_t stream) {
    const float* x = (const float*)d_in[0];  // [N, D]
    const float* a = (const float*)d_in[1];  // [F, D]
    const float* b = (const float*)d_in[2];  // [F]
    const float* W = (const float*)d_in[3];  // [F*M]
    float* out = (float*)d_out;              // [N, M]

    if (ws_size >= (size_t)WS_NEEDED) {
        unsigned short* ws_a1 = (unsigned short*)((char*)d_ws + WS_A1_OFF);
        unsigned short* ws_a2 = (unsigned short*)((char*)d_ws + WS_A2_OFF);
        float*          ws_bs = (float*)((char*)d_ws + WS_BS_OFF);
        km_prep<<<dim3(128), dim3(256), 0, stream>>>(a, b, W, ws_a1, ws_a2, ws_bs);
        km_mfma<<<dim3(NPTS / 64), dim3(512), 0, stream>>>(x, ws_a1, ws_a2, ws_bs, out);
    } else {
        km_fused<<<dim3(NPTS / FB_ROWS), dim3(FB_BLOCK), 0, stream>>>(x, a, b, W, out);
    }
}

// Round 9
// 29.782 us; speedup vs baseline: 1.2299x; 1.2299x over previous
//
#include <hip/hip_runtime.h>
#include <hip/hip_bf16.h>
#include <math.h>

// Problem constants: N=32768 points, D=16, F=4096 features, M=16
#define NPTS  32768
#define DIMD  16
#define NFEAT 4096
#define MDIM  16

typedef short bf16x8 __attribute__((ext_vector_type(8)));
typedef float f32x16 __attribute__((ext_vector_type(16)));
typedef float f32x4v __attribute__((ext_vector_type(4)));

constexpr float SCALE  = 0.02209708691207961f;   // sqrt(2/4096), folded into W at prep
constexpr float INV2PI = 0.15915494309189535f;   // folded into a,b at prep (cos in revs)

// ---- d_ws scratch layout ----
// A1 (a*INV2PI bf16 A-frags): [128 steps][64 lanes][8 bf16]    @ 0       (128 KiB)
// A2 (W*SCALE bf16 A-frags):  [128 steps][2 tiles][64][8 bf16] @ 128 KiB (256 KiB)
// BS (b*INV2PI fp32):         [4096]                           @ 384 KiB ( 16 KiB)
#define WS_A1_OFF 0
#define WS_A2_OFF 131072
#define WS_BS_OFF 393216
#define WS_NEEDED 409600

__device__ __forceinline__ unsigned short f2bf(float x) {  // RNE f32->bf16
    unsigned int u = __float_as_uint(x);
    u += 0x7fff + ((u >> 16) & 1);
    return (unsigned short)(u >> 16);
}
__device__ __forceinline__ unsigned int cvtpk(float lo, float hi) {
    unsigned int r;
    asm("v_cvt_pk_bf16_f32 %0, %1, %2" : "=v"(r) : "v"(lo), "v"(hi));
    return r;
}
// a' = [a_lo | b_lo], b' = [a_hi | b_hi]  (lane halves)
__device__ __forceinline__ void swap32(unsigned int& a, unsigned int& b) {
    asm("v_permlane32_swap_b32 %0, %1" : "+v"(a), "+v"(b));
}

// Wave-parallel prep: block=256 (4 waves), one step per block; wave roles:
// w0 -> A1 frags, w1 -> A2 q=0, w2 -> A2 q=1 (zero-padded m>=16), w3 -> bias.
// MFMA 32x32x16 A-layout: lane l holds row (l&31), k = (l>>5)*8 + j.
__global__ __launch_bounds__(256) void km_prep(
    const float* __restrict__ a, const float* __restrict__ b, const float* __restrict__ W,
    unsigned short* __restrict__ ws_a1, unsigned short* __restrict__ ws_a2,
    float* __restrict__ ws_bs)
{
    const int s  = blockIdx.x;    // K-step 0..127 (32 features each)
    const int wv = threadIdx.x >> 6;
    const int l  = threadIdx.x & 63;
    const int h  = l >> 5;
    const int nl = l & 31;

    if (wv == 0) {        // A1: rows = features 32s+(l&31), k = dims 8h..8h+7, *1/2pi
        const int f = 32 * s + nl;
        const float* ap = a + f * DIMD + 8 * h;
        union { unsigned short u[8]; bf16x8 v; } cv;
        #pragma unroll
        for (int j = 0; j < 8; ++j) cv.u[j] = f2bf(ap[j] * INV2PI);
        *reinterpret_cast<bf16x8*>(ws_a1 + ((size_t)s * 64 + l) * 8) = cv.v;
    } else if (wv <= 2) { // A2 q=wv-1: rows = m (pad m>=16 with 0), k = features
        const int q = wv - 1;
        union { unsigned short u[8]; bf16x8 v; } cv;
        #pragma unroll
        for (int j = 0; j < 8; ++j) {
            float v = 0.f;
            if (nl < MDIM) {
                const int f = 32 * s + 16 * q + 8 * h + j;
                v = W[(size_t)f * MDIM + nl] * SCALE;
            }
            cv.u[j] = f2bf(v);
        }
        *reinterpret_cast<bf16x8*>(ws_a2 + (((size_t)s * 2 + q) * 64 + l) * 8) = cv.v;
    } else {
        if (l < 32) ws_bs[32 * s + l] = b[32 * s + l] * INV2PI;
    }
}

// pack: S (32x32x16 C-layout, lane nl = col n, regs = 16 f-rows) -> two GEMM2
// B-frags (16f x 32n each). Verified layout (rounds 2-4,7 passed with this).
#define KM_PACK(S, P0, P1)                                                            \
    {                                                                                 \
        unsigned int dw0 = cvtpk(__builtin_amdgcn_cosf(S[ 0]), __builtin_amdgcn_cosf(S[ 1])); \
        unsigned int dw1 = cvtpk(__builtin_amdgcn_cosf(S[ 2]), __builtin_amdgcn_cosf(S[ 3])); \
        unsigned int dw2 = cvtpk(__builtin_amdgcn_cosf(S[ 4]), __builtin_amdgcn_cosf(S[ 5])); \
        unsigned int dw3 = cvtpk(__builtin_amdgcn_cosf(S[ 6]), __builtin_amdgcn_cosf(S[ 7])); \
        unsigned int dw4 = cvtpk(__builtin_amdgcn_cosf(S[ 8]), __builtin_amdgcn_cosf(S[ 9])); \
        unsigned int dw5 = cvtpk(__builtin_amdgcn_cosf(S[10]), __builtin_amdgcn_cosf(S[11])); \
        unsigned int dw6 = cvtpk(__builtin_amdgcn_cosf(S[12]), __builtin_amdgcn_cosf(S[13])); \
        unsigned int dw7 = cvtpk(__builtin_amdgcn_cosf(S[14]), __builtin_amdgcn_cosf(S[15])); \
        swap32(dw0, dw2); swap32(dw1, dw3);                                           \
        swap32(dw4, dw6); swap32(dw5, dw7);                                           \
        union { unsigned int u[4]; bf16x8 v; } q0_, q1_;                              \
        q0_.u[0] = dw0; q0_.u[1] = dw1; q0_.u[2] = dw2; q0_.u[3] = dw3;               \
        q1_.u[0] = dw4; q1_.u[1] = dw5; q1_.u[2] = dw6; q1_.u[3] = dw7;               \
        P0 = q0_.v; P1 = q1_.v;                                                       \
    }

// Main: 512 blocks x 512 thr, T=2 n-tiles. EXACT round-3 verified dataflow
// (per-tile serialized GEMM1 -> pack -> GEMM2, valid-masked a2 loads).
// Only inert scheduling levers added: unroll 4 (body unchanged) and
// s_setprio(1) around MFMA clusters (waves are barrier-free in the K-loop,
// so priority arbitration has phase diversity to exploit).
__global__ __launch_bounds__(512, 4) void km_mfma(
    const float* __restrict__ x,
    const unsigned short* __restrict__ ws_a1, const unsigned short* __restrict__ ws_a2,
    const float* __restrict__ ws_bs, float* __restrict__ out)
{
    const int tid = threadIdx.x;
    const int l   = tid & 63;
    const int w   = tid >> 6;          // wave = feature chunk 0..7
    const int h   = l >> 5;
    const int nl  = l & 31;
    const int rowbase = blockIdx.x * 64;

    // GEMM1 B-frags: x^T[16d x 32n] per tile; lane: col n, k = d = 8h+j.
    bf16x8 xf0, xf1;
    {
        union { unsigned short u[8]; bf16x8 v; } c0, c1;
        const float* xp0 = x + (size_t)(rowbase +  0 + nl) * DIMD + 8 * h;
        const float* xp1 = x + (size_t)(rowbase + 32 + nl) * DIMD + 8 * h;
        #pragma unroll
        for (int j = 0; j < 8; ++j) { c0.u[j] = f2bf(xp0[j]); c1.u[j] = f2bf(xp1[j]); }
        xf0 = c0.v; xf1 = c1.v;
    }

    f32x16 acc0, acc1;
    #pragma unroll
    for (int i = 0; i < 16; ++i) { acc0[i] = 0.f; acc1[i] = 0.f; }

    const bool valid = (nl < MDIM);

    #pragma unroll 4
    for (int s = 0; s < 16; ++s) {
        const int sg = w * 16 + s;
        const int F0 = 32 * sg;

        bf16x8 a1 = *reinterpret_cast<const bf16x8*>(ws_a1 + ((size_t)sg * 64 + l) * 8);
        bf16x8 a2t0 = {}, a2t1 = {};
        if (valid) {
            a2t0 = *reinterpret_cast<const bf16x8*>(ws_a2 + (((size_t)sg * 2 + 0) * 64 + l) * 8);
            a2t1 = *reinterpret_cast<const bf16x8*>(ws_a2 + (((size_t)sg * 2 + 1) * 64 + l) * 8);
        }

        // ---- tile 0 ----
        {
            f32x16 c;   // bias C-in: c[r] = bs[F0 + (r&3) + 8*(r>>2) + 4h], prescaled
            #pragma unroll
            for (int g = 0; g < 4; ++g) {
                f32x4v bb = *reinterpret_cast<const f32x4v*>(ws_bs + F0 + 8 * g + 4 * h);
                c[4*g] = bb[0]; c[4*g+1] = bb[1]; c[4*g+2] = bb[2]; c[4*g+3] = bb[3];
            }
            __builtin_amdgcn_s_setprio(1);
            f32x16 S = __builtin_amdgcn_mfma_f32_32x32x16_bf16(a1, xf0, c, 0, 0, 0);
            __builtin_amdgcn_s_setprio(0);
            bf16x8 p0, p1;
            KM_PACK(S, p0, p1)
            __builtin_amdgcn_s_setprio(1);
            acc0 = __builtin_amdgcn_mfma_f32_32x32x16_bf16(a2t0, p0, acc0, 0, 0, 0);
            acc0 = __builtin_amdgcn_mfma_f32_32x32x16_bf16(a2t1, p1, acc0, 0, 0, 0);
            __builtin_amdgcn_s_setprio(0);
        }
        // ---- tile 1 (bias reload is an L1 hit / CSE'd) ----
        {
            f32x16 c;
            #pragma unroll
            for (int g = 0; g < 4; ++g) {
                f32x4v bb = *reinterpret_cast<const f32x4v*>(ws_bs + F0 + 8 * g + 4 * h);
                c[4*g] = bb[0]; c[4*g+1] = bb[1]; c[4*g+2] = bb[2]; c[4*g+3] = bb[3];
            }
            __builtin_amdgcn_s_setprio(1);
            f32x16 S = __builtin_amdgcn_mfma_f32_32x32x16_bf16(a1, xf1, c, 0, 0, 0);
            __builtin_amdgcn_s_setprio(0);
            bf16x8 p0, p1;
            KM_PACK(S, p0, p1)
            __builtin_amdgcn_s_setprio(1);
            acc1 = __builtin_amdgcn_mfma_f32_32x32x16_bf16(a2t0, p0, acc1, 0, 0, 0);
            acc1 = __builtin_amdgcn_mfma_f32_32x32x16_bf16(a2t1, p1, acc1, 0, 0, 0);
            __builtin_amdgcn_s_setprio(0);
        }
    }

    // Cross-wave reduce. acc regs 0..7 hold m=(r&3)+8*(r>>2)+4h for col n=nl
    // (regs 8-15 are the zero m>=16 pad).
    __shared__ float red[2][8][64][8];   // 32 KiB
    #pragma unroll
    for (int r = 0; r < 8; ++r) { red[0][w][l][r] = acc0[r]; red[1][w][l][r] = acc1[r]; }
    __syncthreads();

    const int n_l = tid >> 4;
    const int m   = tid & 15;
    const int li  = n_l + 32 * ((m >> 2) & 1);
    const int r   = (m & 3) + 4 * (m >> 3);
    float s0 = 0.f, s1 = 0.f;
    #pragma unroll
    for (int ww = 0; ww < 8; ++ww) { s0 += red[0][ww][li][r]; s1 += red[1][ww][li][r]; }
    out[(size_t)(rowbase +  0 + n_l) * MDIM + m] = s0;
    out[(size_t)(rowbase + 32 + n_l) * MDIM + m] = s1;
}

// ---------------- fallback (round-1 kernel, known-correct) ----------------
constexpr int FB_WAVES = 8, FB_BLOCK = 512, FB_ROWS = 64, FB_FPW = NFEAT / FB_WAVES;
__global__ __launch_bounds__(FB_BLOCK) void km_fused(
    const float* __restrict__ x, const float* __restrict__ a,
    const float* __restrict__ b, const float* __restrict__ W,
    float* __restrict__ out)
{
    const int lane = threadIdx.x & 63, wave = threadIdx.x >> 6;
    const int row  = blockIdx.x * FB_ROWS + lane;
    float xr[DIMD];
    const float4* xp = reinterpret_cast<const float4*>(x + (size_t)row * DIMD);
    #pragma unroll
    for (int i = 0; i < 4; ++i) {
        float4 v = xp[i];
        xr[4*i] = v.x; xr[4*i+1] = v.y; xr[4*i+2] = v.z; xr[4*i+3] = v.w;
    }
    float acc[MDIM];
    #pragma unroll
    for (int m = 0; m < MDIM; ++m) acc[m] = 0.f;
    const int fbase = __builtin_amdgcn_readfirstlane(wave * FB_FPW);
    const float* ab = a + (size_t)fbase * DIMD;
    const float* wb = W + (size_t)fbase * MDIM;
    const float* bb = b + fbase;
    #pragma unroll 2
    for (int fi = 0; fi < FB_FPW; ++fi) {
        const float* ar = ab + fi * DIMD;
        const float* wr = wb + fi * MDIM;
        float d0 = 0.f, d1 = 0.f, d2 = 0.f, d3 = 0.f;
        #pragma unroll
        for (int d = 0; d < 4; ++d) {
            d0 = fmaf(xr[d], ar[d], d0);       d1 = fmaf(xr[4+d], ar[4+d], d1);
            d2 = fmaf(xr[8+d], ar[8+d], d2);   d3 = fmaf(xr[12+d], ar[12+d], d3);
        }
        float t = ((d0 + d1) + (d2 + d3)) + bb[fi];
        float cc = __builtin_amdgcn_cosf(t * INV2PI);
        #pragma unroll
        for (int m = 0; m < MDIM; ++m) acc[m] = fmaf(cc, wr[m], acc[m]);
    }
    __shared__ float red[FB_WAVES][FB_ROWS][MDIM];
    #pragma unroll
    for (int m = 0; m < MDIM; m += 4)
        *reinterpret_cast<float4*>(&red[wave][lane][m]) =
            make_float4(acc[m], acc[m+1], acc[m+2], acc[m+3]);
    __syncthreads();
    for (int o = threadIdx.x; o < FB_ROWS * MDIM; o += FB_BLOCK) {
        const int rr = o >> 4, m = o & 15;
        float s = 0.f;
        #pragma unroll
        for (int ww = 0; ww < FB_WAVES; ++ww) s += red[ww][rr][m];
        out[((size_t)blockIdx.x * FB_ROWS + rr) * MDIM + m] = s * SCALE;
    }
}

extern "C" void kernel_launch(void* const* d_in, const int* in_sizes, int n_in,
                              void* d_out, int out_size, void* d_ws, size_t ws_size,
                              hipStream_t stream) {
    const float* x = (const float*)d_in[0];  // [N, D]
    const float* a = (const float*)d_in[1];  // [F, D]
    const float* b = (const float*)d_in[2];  // [F]
    const float* W = (const float*)d_in[3];  // [F*M]
    float* out = (float*)d_out;              // [N, M]

    if (ws_size >= (size_t)WS_NEEDED) {
        unsigned short* ws_a1 = (unsigned short*)((char*)d_ws + WS_A1_OFF);
        unsigned short* ws_a2 = (unsigned short*)((char*)d_ws + WS_A2_OFF);
        float*          ws_bs = (float*)((char*)d_ws + WS_BS_OFF);
        km_prep<<<dim3(128), dim3(256), 0, stream>>>(a, b, W, ws_a1, ws_a2, ws_bs);
        km_mfma<<<dim3(NPTS / 64), dim3(512), 0, stream>>>(x, ws_a1, ws_a2, ws_bs, out);
    } else {
        km_fused<<<dim3(NPTS / FB_ROWS), dim3(FB_BLOCK), 0, stream>>>(x, a, b, W, out);
    }
}

// Round 10
// 28.799 us; speedup vs baseline: 1.2719x; 1.0341x over previous
//
#include <hip/hip_runtime.h>
#include <hip/hip_bf16.h>
#include <math.h>

// Problem constants: N=32768 points, D=16, F=4096 features, M=16
#define NPTS  32768
#define DIMD  16
#define NFEAT 4096
#define MDIM  16

typedef short bf16x8 __attribute__((ext_vector_type(8)));
typedef float f32x16 __attribute__((ext_vector_type(16)));
typedef float f32x4v __attribute__((ext_vector_type(4)));

constexpr float SCALE  = 0.02209708691207961f;   // sqrt(2/4096), folded into W at prep
constexpr float INV2PI = 0.15915494309189535f;   // folded into a,b at prep (cos in revs)

// ---- d_ws scratch layout ----
// A1 (a*INV2PI bf16 A-frags): [128 steps][64 lanes][8 bf16]    @ 0       (128 KiB)
// A2 (W*SCALE bf16 A-frags):  [128 steps][2 tiles][64][8 bf16] @ 128 KiB (256 KiB)
// BS (b*INV2PI fp32):         [4096]                           @ 384 KiB ( 16 KiB)
#define WS_A1_OFF 0
#define WS_A2_OFF 131072
#define WS_BS_OFF 393216
#define WS_NEEDED 409600

__device__ __forceinline__ unsigned short f2bf(float x) {  // RNE f32->bf16
    unsigned int u = __float_as_uint(x);
    u += 0x7fff + ((u >> 16) & 1);
    return (unsigned short)(u >> 16);
}
__device__ __forceinline__ unsigned int cvtpk(float lo, float hi) {
    unsigned int r;
    asm("v_cvt_pk_bf16_f32 %0, %1, %2" : "=v"(r) : "v"(lo), "v"(hi));
    return r;
}
// a' = [a_lo | b_lo], b' = [a_hi | b_hi]  (lane halves)
__device__ __forceinline__ void swap32(unsigned int& a, unsigned int& b) {
    asm("v_permlane32_swap_b32 %0, %1" : "+v"(a), "+v"(b));
}

// Wave-parallel prep: block=256 (4 waves), one step per block; wave roles:
// w0 -> A1 frags, w1 -> A2 q=0, w2 -> A2 q=1 (zero-padded m>=16), w3 -> bias.
// MFMA 32x32x16 A-layout: lane l holds row (l&31), k = (l>>5)*8 + j.
__global__ __launch_bounds__(256) void km_prep(
    const float* __restrict__ a, const float* __restrict__ b, const float* __restrict__ W,
    unsigned short* __restrict__ ws_a1, unsigned short* __restrict__ ws_a2,
    float* __restrict__ ws_bs)
{
    const int s  = blockIdx.x;    // K-step 0..127 (32 features each)
    const int wv = threadIdx.x >> 6;
    const int l  = threadIdx.x & 63;
    const int h  = l >> 5;
    const int nl = l & 31;

    if (wv == 0) {        // A1: rows = features 32s+(l&31), k = dims 8h..8h+7, *1/2pi
        const int f = 32 * s + nl;
        const float* ap = a + f * DIMD + 8 * h;
        union { unsigned short u[8]; bf16x8 v; } cv;
        #pragma unroll
        for (int j = 0; j < 8; ++j) cv.u[j] = f2bf(ap[j] * INV2PI);
        *reinterpret_cast<bf16x8*>(ws_a1 + ((size_t)s * 64 + l) * 8) = cv.v;
    } else if (wv <= 2) { // A2 q=wv-1: rows = m (pad m>=16 with 0), k = features
        const int q = wv - 1;
        union { unsigned short u[8]; bf16x8 v; } cv;
        #pragma unroll
        for (int j = 0; j < 8; ++j) {
            float v = 0.f;
            if (nl < MDIM) {
                const int f = 32 * s + 16 * q + 8 * h + j;
                v = W[(size_t)f * MDIM + nl] * SCALE;
            }
            cv.u[j] = f2bf(v);
        }
        *reinterpret_cast<bf16x8*>(ws_a2 + (((size_t)s * 2 + q) * 64 + l) * 8) = cv.v;
    } else {
        if (l < 32) ws_bs[32 * s + l] = b[32 * s + l] * INV2PI;
    }
}

// pack: S (32x32x16 C-layout, lane nl = col n, regs = 16 f-rows) -> two GEMM2
// B-frags (16f x 32n each). Verified layout (rounds 2-4,7,9 passed with this).
#define KM_PACK(S, P0, P1)                                                            \
    {                                                                                 \
        unsigned int dw0 = cvtpk(__builtin_amdgcn_cosf(S[ 0]), __builtin_amdgcn_cosf(S[ 1])); \
        unsigned int dw1 = cvtpk(__builtin_amdgcn_cosf(S[ 2]), __builtin_amdgcn_cosf(S[ 3])); \
        unsigned int dw2 = cvtpk(__builtin_amdgcn_cosf(S[ 4]), __builtin_amdgcn_cosf(S[ 5])); \
        unsigned int dw3 = cvtpk(__builtin_amdgcn_cosf(S[ 6]), __builtin_amdgcn_cosf(S[ 7])); \
        unsigned int dw4 = cvtpk(__builtin_amdgcn_cosf(S[ 8]), __builtin_amdgcn_cosf(S[ 9])); \
        unsigned int dw5 = cvtpk(__builtin_amdgcn_cosf(S[10]), __builtin_amdgcn_cosf(S[11])); \
        unsigned int dw6 = cvtpk(__builtin_amdgcn_cosf(S[12]), __builtin_amdgcn_cosf(S[13])); \
        unsigned int dw7 = cvtpk(__builtin_amdgcn_cosf(S[14]), __builtin_amdgcn_cosf(S[15])); \
        swap32(dw0, dw2); swap32(dw1, dw3);                                           \
        swap32(dw4, dw6); swap32(dw5, dw7);                                           \
        union { unsigned int u[4]; bf16x8 v; } q0_, q1_;                              \
        q0_.u[0] = dw0; q0_.u[1] = dw1; q0_.u[2] = dw2; q0_.u[3] = dw3;               \
        q1_.u[0] = dw4; q1_.u[1] = dw5; q1_.u[2] = dw6; q1_.u[3] = dw7;               \
        P0 = q0_.v; P1 = q1_.v;                                                       \
    }

// Main: 512 blocks x 512 thr, T=2 n-tiles. Round-3 verified dataflow, best
// measured config (29.13 us): per-tile serialized GEMM1 -> pack -> GEMM2,
// valid-masked a2 loads, unroll 2, no setprio (R9 showed both neutral).
// This kernel is transcendental-issue-bound: 134M v_cos is the irreducible
// floor; traffic/occupancy/scheduling levers all measured flat (R4,R9) or
// negative (R7 poly-hybrid); dual-GEMM1 restructures broke numerics (R6,R8).
__global__ __launch_bounds__(512, 4) void km_mfma(
    const float* __restrict__ x,
    const unsigned short* __restrict__ ws_a1, const unsigned short* __restrict__ ws_a2,
    const float* __restrict__ ws_bs, float* __restrict__ out)
{
    const int tid = threadIdx.x;
    const int l   = tid & 63;
    const int w   = tid >> 6;          // wave = feature chunk 0..7
    const int h   = l >> 5;
    const int nl  = l & 31;
    const int rowbase = blockIdx.x * 64;

    // GEMM1 B-frags: x^T[16d x 32n] per tile; lane: col n, k = d = 8h+j.
    bf16x8 xf0, xf1;
    {
        union { unsigned short u[8]; bf16x8 v; } c0, c1;
        const float* xp0 = x + (size_t)(rowbase +  0 + nl) * DIMD + 8 * h;
        const float* xp1 = x + (size_t)(rowbase + 32 + nl) * DIMD + 8 * h;
        #pragma unroll
        for (int j = 0; j < 8; ++j) { c0.u[j] = f2bf(xp0[j]); c1.u[j] = f2bf(xp1[j]); }
        xf0 = c0.v; xf1 = c1.v;
    }

    f32x16 acc0, acc1;
    #pragma unroll
    for (int i = 0; i < 16; ++i) { acc0[i] = 0.f; acc1[i] = 0.f; }

    const bool valid = (nl < MDIM);

    #pragma unroll 2
    for (int s = 0; s < 16; ++s) {
        const int sg = w * 16 + s;
        const int F0 = 32 * sg;

        bf16x8 a1 = *reinterpret_cast<const bf16x8*>(ws_a1 + ((size_t)sg * 64 + l) * 8);
        bf16x8 a2t0 = {}, a2t1 = {};
        if (valid) {
            a2t0 = *reinterpret_cast<const bf16x8*>(ws_a2 + (((size_t)sg * 2 + 0) * 64 + l) * 8);
            a2t1 = *reinterpret_cast<const bf16x8*>(ws_a2 + (((size_t)sg * 2 + 1) * 64 + l) * 8);
        }

        // ---- tile 0 ----
        {
            f32x16 c;   // bias C-in: c[r] = bs[F0 + (r&3) + 8*(r>>2) + 4h], prescaled
            #pragma unroll
            for (int g = 0; g < 4; ++g) {
                f32x4v bb = *reinterpret_cast<const f32x4v*>(ws_bs + F0 + 8 * g + 4 * h);
                c[4*g] = bb[0]; c[4*g+1] = bb[1]; c[4*g+2] = bb[2]; c[4*g+3] = bb[3];
            }
            f32x16 S = __builtin_amdgcn_mfma_f32_32x32x16_bf16(a1, xf0, c, 0, 0, 0);
            bf16x8 p0, p1;
            KM_PACK(S, p0, p1)
            acc0 = __builtin_amdgcn_mfma_f32_32x32x16_bf16(a2t0, p0, acc0, 0, 0, 0);
            acc0 = __builtin_amdgcn_mfma_f32_32x32x16_bf16(a2t1, p1, acc0, 0, 0, 0);
        }
        // ---- tile 1 (bias reload is an L1 hit) ----
        {
            f32x16 c;
            #pragma unroll
            for (int g = 0; g < 4; ++g) {
                f32x4v bb = *reinterpret_cast<const f32x4v*>(ws_bs + F0 + 8 * g + 4 * h);
                c[4*g] = bb[0]; c[4*g+1] = bb[1]; c[4*g+2] = bb[2]; c[4*g+3] = bb[3];
            }
            f32x16 S = __builtin_amdgcn_mfma_f32_32x32x16_bf16(a1, xf1, c, 0, 0, 0);
            bf16x8 p0, p1;
            KM_PACK(S, p0, p1)
            acc1 = __builtin_amdgcn_mfma_f32_32x32x16_bf16(a2t0, p0, acc1, 0, 0, 0);
            acc1 = __builtin_amdgcn_mfma_f32_32x32x16_bf16(a2t1, p1, acc1, 0, 0, 0);
        }
    }

    // Cross-wave reduce. acc regs 0..7 hold m=(r&3)+8*(r>>2)+4h for col n=nl
    // (regs 8-15 are the zero m>=16 pad).
    __shared__ float red[2][8][64][8];   // 32 KiB
    #pragma unroll
    for (int r = 0; r < 8; ++r) { red[0][w][l][r] = acc0[r]; red[1][w][l][r] = acc1[r]; }
    __syncthreads();

    const int n_l = tid >> 4;
    const int m   = tid & 15;
    const int li  = n_l + 32 * ((m >> 2) & 1);
    const int r   = (m & 3) + 4 * (m >> 3);
    float s0 = 0.f, s1 = 0.f;
    #pragma unroll
    for (int ww = 0; ww < 8; ++ww) { s0 += red[0][ww][li][r]; s1 += red[1][ww][li][r]; }
    out[(size_t)(rowbase +  0 + n_l) * MDIM + m] = s0;
    out[(size_t)(rowbase + 32 + n_l) * MDIM + m] = s1;
}

// ---------------- fallback (round-1 kernel, known-correct) ----------------
constexpr int FB_WAVES = 8, FB_BLOCK = 512, FB_ROWS = 64, FB_FPW = NFEAT / FB_WAVES;
__global__ __launch_bounds__(FB_BLOCK) void km_fused(
    const float* __restrict__ x, const float* __restrict__ a,
    const float* __restrict__ b, const float* __restrict__ W,
    float* __restrict__ out)
{
    const int lane = threadIdx.x & 63, wave = threadIdx.x >> 6;
    const int row  = blockIdx.x * FB_ROWS + lane;
    float xr[DIMD];
    const float4* xp = reinterpret_cast<const float4*>(x + (size_t)row * DIMD);
    #pragma unroll
    for (int i = 0; i < 4; ++i) {
        float4 v = xp[i];
        xr[4*i] = v.x; xr[4*i+1] = v.y; xr[4*i+2] = v.z; xr[4*i+3] = v.w;
    }
    float acc[MDIM];
    #pragma unroll
    for (int m = 0; m < MDIM; ++m) acc[m] = 0.f;
    const int fbase = __builtin_amdgcn_readfirstlane(wave * FB_FPW);
    const float* ab = a + (size_t)fbase * DIMD;
    const float* wb = W + (size_t)fbase * MDIM;
    const float* bb = b + fbase;
    #pragma unroll 2
    for (int fi = 0; fi < FB_FPW; ++fi) {
        const float* ar = ab + fi * DIMD;
        const float* wr = wb + fi * MDIM;
        float d0 = 0.f, d1 = 0.f, d2 = 0.f, d3 = 0.f;
        #pragma unroll
        for (int d = 0; d < 4; ++d) {
            d0 = fmaf(xr[d], ar[d], d0);       d1 = fmaf(xr[4+d], ar[4+d], d1);
            d2 = fmaf(xr[8+d], ar[8+d], d2);   d3 = fmaf(xr[12+d], ar[12+d], d3);
        }
        float t = ((d0 + d1) + (d2 + d3)) + bb[fi];
        float cc = __builtin_amdgcn_cosf(t * INV2PI);
        #pragma unroll
        for (int m = 0; m < MDIM; ++m) acc[m] = fmaf(cc, wr[m], acc[m]);
    }
    __shared__ float red[FB_WAVES][FB_ROWS][MDIM];
    #pragma unroll
    for (int m = 0; m < MDIM; m += 4)
        *reinterpret_cast<float4*>(&red[wave][lane][m]) =
            make_float4(acc[m], acc[m+1], acc[m+2], acc[m+3]);
    __syncthreads();
    for (int o = threadIdx.x; o < FB_ROWS * MDIM; o += FB_BLOCK) {
        const int rr = o >> 4, m = o & 15;
        float s = 0.f;
        #pragma unroll
        for (int ww = 0; ww < FB_WAVES; ++ww) s += red[ww][rr][m];
        out[((size_t)blockIdx.x * FB_ROWS + rr) * MDIM + m] = s * SCALE;
    }
}

extern "C" void kernel_launch(void* const* d_in, const int* in_sizes, int n_in,
                              void* d_out, int out_size, void* d_ws, size_t ws_size,
                              hipStream_t stream) {
    const float* x = (const float*)d_in[0];  // [N, D]
    const float* a = (const float*)d_in[1];  // [F, D]
    const float* b = (const float*)d_in[2];  // [F]
    const float* W = (const float*)d_in[3];  // [F*M]
    float* out = (float*)d_out;              // [N, M]

    if (ws_size >= (size_t)WS_NEEDED) {
        unsigned short* ws_a1 = (unsigned short*)((char*)d_ws + WS_A1_OFF);
        unsigned short* ws_a2 = (unsigned short*)((char*)d_ws + WS_A2_OFF);
        float*          ws_bs = (float*)((char*)d_ws + WS_BS_OFF);
        km_prep<<<dim3(128), dim3(256), 0, stream>>>(a, b, W, ws_a1, ws_a2, ws_bs);
        km_mfma<<<dim3(NPTS / 64), dim3(512), 0, stream>>>(x, ws_a1, ws_a2, ws_bs, out);
    } else {
        km_fused<<<dim3(NPTS / FB_ROWS), dim3(FB_BLOCK), 0, stream>>>(x, a, b, W, out);
    }
}